// Round 4
// baseline (386.063 us; speedup 1.0000x reference)
//
#include <hip/hip_runtime.h>
#include <hip/hip_bf16.h>

#define GG 64      // B*N graphs
#define LN 2048    // nodes per graph
#define BB 4       // batch
#define NS 16      // sets per batch
#define EE 16384   // edges
#define C_0 64
#define CH 128
#define EPSV 1e-5f
#define VK 16      // variance atomic spread copies
// sliced layout: 8 slices of (32 graphs x 32 ch); slice id = (g>>5)*4 + (c>>5)
// elem addr = sid*SLICE + l*1024 + (g&31)*32 + (c&31)
#define SLICE ((size_t)LN * 1024)

using bf16x8 = __attribute__((ext_vector_type(8))) short;
using f32x4  = __attribute__((ext_vector_type(4))) float;

__device__ __forceinline__ float b2f(unsigned short u) {
    union { unsigned int i; float f; } v; v.i = ((unsigned int)u) << 16; return v.f;
}
__device__ __forceinline__ unsigned short f2b(float f) {
    union { float f; unsigned int i; } v; v.f = f;
    unsigned int r = v.i + 0x7fffu + ((v.i >> 16) & 1u);   // RNE
    return (unsigned short)(r >> 16);
}
__device__ __forceinline__ void acc4(float* acc, uint2 v, float w) {
    acc[0] += w * b2f((unsigned short)(v.x & 0xffffu));
    acc[1] += w * b2f((unsigned short)(v.x >> 16));
    acc[2] += w * b2f((unsigned short)(v.y & 0xffffu));
    acc[3] += w * b2f((unsigned short)(v.y >> 16));
}

// ---------- graph preprocessing ----------
__global__ void k_deg(const int* __restrict__ dst, int* __restrict__ cnt) {
    int e = blockIdx.x * blockDim.x + threadIdx.x;
    if (e < EE) atomicAdd(&cnt[dst[e]], 1);
}

__global__ void k_node(const int* __restrict__ cnt, float* __restrict__ dinv,
                       float* __restrict__ selfc) {
    int l = blockIdx.x * blockDim.x + threadIdx.x;
    if (l < LN) {
        float d = (float)cnt[l] + 2.0f;   // improved GCN: A + 2I
        float di = rsqrtf(d);
        dinv[l] = di;
        selfc[l] = 2.0f * di * di;
    }
}

__global__ void k_scan(const int* __restrict__ cnt, int* __restrict__ off) {
    __shared__ int part[256];
    __shared__ int pre[256];
    int t = threadIdx.x;
    int base = t * 8;
    int loc[8];
    int s = 0;
#pragma unroll
    for (int i = 0; i < 8; i++) { loc[i] = cnt[base + i]; s += loc[i]; }
    part[t] = s;
    __syncthreads();
    if (t == 0) {
        int run = 0;
        for (int i = 0; i < 256; i++) { pre[i] = run; run += part[i]; }
        off[LN] = run;
    }
    __syncthreads();
    int run = pre[t];
#pragma unroll
    for (int i = 0; i < 8; i++) { off[base + i] = run; run += loc[i]; }
}

__global__ void k_fill(const int* __restrict__ src, const int* __restrict__ dst,
                       const int* __restrict__ off, int* __restrict__ cur,
                       const float* __restrict__ dinv,
                       int* __restrict__ ssrc, float* __restrict__ snorm) {
    int e = blockIdx.x * blockDim.x + threadIdx.x;
    if (e < EE) {
        int s = src[e], d = dst[e];
        int pos = atomicAdd(&cur[d], 1);
        int idx = off[d] + pos;
        ssrc[idx] = s;
        snorm[idx] = dinv[s] * dinv[d];
    }
}

// ---------- W -> W^T bf16 ----------
__global__ void k_wprep(const float* __restrict__ W, unsigned short* __restrict__ Wt,
                        int K) {
    int idx = blockIdx.x * 256 + threadIdx.x;
    if (idx < K * CH) {
        int k = idx >> 7, c = idx & (CH - 1);
        Wt[c * K + k] = f2b(W[idx]);
    }
}

// ---------- MFMA GEMM: hw[l,g,co] = sum_k A[l,k] * W[k,co] (bf16, fp32 acc) ----------
// FUSE=false: layer 1, A from x fp32 [g][K][LN].
// FUSE=true : A = relu(aPrev * scl + bet)   (aPrev already mean-centered)
template <int K, bool FUSE>
__global__ __launch_bounds__(256) void k_mm(
    const float* __restrict__ X, const unsigned short* __restrict__ Ap,
    const float* __restrict__ scl, const float* __restrict__ bet,
    const unsigned short* __restrict__ Wt, unsigned short* __restrict__ hw)
{
    constexpr int KP = K + 8;                 // LDS k-pad
    __shared__ unsigned short As[64 * KP];
    __shared__ unsigned short Ws[128 * KP];
    const int g = blockIdx.y;
    const int l0 = blockIdx.x * 64;
    const int t = threadIdx.x;
    const int wq = t >> 6;
    const int lane = t & 63;

    // stage W^T tile (c-major, k contiguous)
    {
        const int c = t >> 1;
        const int kq = (t & 1) * (K / 2);
        const unsigned short* wp = Wt + c * K + kq;
        unsigned short* wd = Ws + c * KP + kq;
#pragma unroll
        for (int i = 0; i < K / 2; i += 8)
            *(uint4*)&wd[i] = *(const uint4*)&wp[i];
    }
    if (!FUSE) {
        // x fp32 [g][K][LN] -> As[l][k] bf16 (transpose in LDS)
        const int k = t >> 2;
        const int lq = (t & 3) * 16;
        const float* xp = X + ((size_t)g * K + k) * LN + l0 + lq;
#pragma unroll
        for (int i = 0; i < 16; i += 4) {
            float4 v = *(const float4*)&xp[i];
            As[(lq + i + 0) * KP + k] = f2b(v.x);
            As[(lq + i + 1) * KP + k] = f2b(v.y);
            As[(lq + i + 2) * KP + k] = f2b(v.z);
            As[(lq + i + 3) * KP + k] = f2b(v.w);
        }
    } else {
        // fused prev-layer BN+ReLU during staging; Ap is sliced + centered
        const int l = t >> 2;
        const int sc = t & 3;
        const int kq = sc * 32;
        const int sid = (g >> 5) * 4 + sc;
        const unsigned short* ap = Ap + sid * SLICE + (size_t)(l0 + l) * 1024 +
                                   (g & 31) * 32;
        unsigned short* ad = As + l * KP + kq;
#pragma unroll
        for (int i = 0; i < 32; i += 8) {
            union { uint4 v; unsigned short s[8]; } u;
            u.v = *(const uint4*)&ap[i];
            float4 s0 = *(const float4*)&scl[kq + i];
            float4 s1 = *(const float4*)&scl[kq + i + 4];
            float4 c0 = *(const float4*)&bet[kq + i];
            float4 c1 = *(const float4*)&bet[kq + i + 4];
            union { uint4 v; unsigned short s[8]; } o;
            o.s[0] = f2b(fmaxf(b2f(u.s[0]) * s0.x + c0.x, 0.f));
            o.s[1] = f2b(fmaxf(b2f(u.s[1]) * s0.y + c0.y, 0.f));
            o.s[2] = f2b(fmaxf(b2f(u.s[2]) * s0.z + c0.z, 0.f));
            o.s[3] = f2b(fmaxf(b2f(u.s[3]) * s0.w + c0.w, 0.f));
            o.s[4] = f2b(fmaxf(b2f(u.s[4]) * s1.x + c1.x, 0.f));
            o.s[5] = f2b(fmaxf(b2f(u.s[5]) * s1.y + c1.y, 0.f));
            o.s[6] = f2b(fmaxf(b2f(u.s[6]) * s1.z + c1.z, 0.f));
            o.s[7] = f2b(fmaxf(b2f(u.s[7]) * s1.w + c1.w, 0.f));
            *(uint4*)&ad[i] = o.v;
        }
    }
    __syncthreads();

    f32x4 acc[8];
#pragma unroll
    for (int i = 0; i < 8; i++) acc[i] = (f32x4){0.f, 0.f, 0.f, 0.f};
    const int lr = lane & 15;
    const int kof = (lane >> 4) * 8;
#pragma unroll
    for (int ks = 0; ks < K / 32; ks++) {
        bf16x8 aF = *(const bf16x8*)&As[(wq * 16 + lr) * KP + ks * 32 + kof];
#pragma unroll
        for (int nf = 0; nf < 8; nf++) {
            bf16x8 bF = *(const bf16x8*)&Ws[(nf * 16 + lr) * KP + ks * 32 + kof];
            acc[nf] = __builtin_amdgcn_mfma_f32_16x16x32_bf16(aF, bF, acc[nf], 0, 0, 0);
        }
    }
    __syncthreads();
    // repack D (C/D map: col=lane&15, row=(lane>>4)*4+reg) -> LDS
    unsigned short* Cs = Ws;   // reuse
#pragma unroll
    for (int nf = 0; nf < 8; nf++) {
#pragma unroll
        for (int r = 0; r < 4; r++) {
            int row = wq * 16 + (lane >> 4) * 4 + r;
            int col = nf * 16 + lr;
            Cs[row * 136 + col] = f2b(acc[nf][r]);
        }
    }
    __syncthreads();
    {
        const int l = t >> 2;
        const int sc = t & 3;
        unsigned short* hp = hw + (size_t)((g >> 5) * 4 + sc) * SLICE +
                             (size_t)(l0 + l) * 1024 + (g & 31) * 32;
#pragma unroll
        for (int i = 0; i < 32; i += 8)
            *(uint4*)&hp[i] = *(const uint4*)&Cs[l * 136 + sc * 32 + i];
    }
}

// ---------- fused gather + center + variance, XCD-pinned channel/graph slices ----
// bid = chunk*8 + sid; sid -> XCD (round-robin heuristic); 8 nodes per chunk
// thread: gl = t&31 (graph within slice), cq = t>>5 (4-ch quad within 32-ch slice)
__global__ __launch_bounds__(256) void k_gnv(
    const unsigned short* __restrict__ hw, unsigned short* __restrict__ a,
    float* __restrict__ varK,
    const int* __restrict__ off, const int* __restrict__ ssrc,
    const float* __restrict__ snorm, const float* __restrict__ selfc)
{
    const int bid = blockIdx.x;
    const int sid = bid & 7;
    const int chunk = bid >> 3;          // [0, 256)
    const int l0 = chunk * 8;
    const int t = threadIdx.x;
    const int gl = t & 31;
    const int cq = t >> 5;
    const int go = gl * 32 + cq * 4;
    const unsigned short* hws = hw + sid * SLICE;
    unsigned short* aBs = a + sid * SLICE;

    float vacc[4] = {0.f, 0.f, 0.f, 0.f};
#pragma unroll 2
    for (int i = 0; i < 8; i++) {
        const int l = l0 + i;
        float acc[4];
        {
            uint2 v = *(const uint2*)&hws[(size_t)l * 1024 + go];
            const float sc = selfc[l];
            acc[0] = sc * b2f((unsigned short)(v.x & 0xffffu));
            acc[1] = sc * b2f((unsigned short)(v.x >> 16));
            acc[2] = sc * b2f((unsigned short)(v.y & 0xffffu));
            acc[3] = sc * b2f((unsigned short)(v.y >> 16));
        }
        const int s0 = off[l], s1 = off[l + 1];
        int e = s0;
        for (; e + 4 <= s1; e += 4) {
            int sA = ssrc[e], sB = ssrc[e + 1], sC = ssrc[e + 2], sD = ssrc[e + 3];
            float wA = snorm[e], wB = snorm[e + 1], wC = snorm[e + 2], wD = snorm[e + 3];
            uint2 vA = *(const uint2*)&hws[(size_t)sA * 1024 + go];
            uint2 vB = *(const uint2*)&hws[(size_t)sB * 1024 + go];
            uint2 vC = *(const uint2*)&hws[(size_t)sC * 1024 + go];
            uint2 vD = *(const uint2*)&hws[(size_t)sD * 1024 + go];
            acc4(acc, vA, wA); acc4(acc, vB, wB);
            acc4(acc, vC, wC); acc4(acc, vD, wD);
        }
        for (; e < s1; e++) {
            int sA = ssrc[e];
            float wA = snorm[e];
            uint2 vA = *(const uint2*)&hws[(size_t)sA * 1024 + go];
            acc4(acc, vA, wA);
        }
        // mean over the 16 sets: n-index == lane&15 (butterfly keeps all lanes valid)
        float m[4] = {acc[0], acc[1], acc[2], acc[3]};
#pragma unroll
        for (int mask = 1; mask <= 8; mask <<= 1) {
#pragma unroll
            for (int j = 0; j < 4; j++) m[j] += __shfl_xor(m[j], mask, 64);
        }
        unsigned short ob[4];
#pragma unroll
        for (int j = 0; j < 4; j++) {
            float d = acc[j] - m[j] * (1.f / NS);   // centered value
            vacc[j] += d * d;
            ob[j] = f2b(d);
        }
        unsigned long long packed =
            (unsigned long long)ob[0] | ((unsigned long long)ob[1] << 16) |
            ((unsigned long long)ob[2] << 32) | ((unsigned long long)ob[3] << 48);
        __builtin_nontemporal_store(
            packed, (unsigned long long*)&aBs[(size_t)l * 1024 + go]);
    }
    // deferred variance butterfly + one atomic burst per 16-lane group
#pragma unroll
    for (int mask = 1; mask <= 8; mask <<= 1) {
#pragma unroll
        for (int j = 0; j < 4; j++) vacc[j] += __shfl_xor(vacc[j], mask, 64);
    }
    if ((t & 15) == 0) {
        float* vp = &varK[(chunk & (VK - 1)) * CH + (sid & 3) * 32 + cq * 4];
#pragma unroll
        for (int j = 0; j < 4; j++) atomicAdd(&vp[j], vacc[j]);
    }
}

__global__ void k_scale(const float* __restrict__ varK, const float* __restrict__ gam,
                        float* __restrict__ scl) {
    int c = threadIdx.x;
    float v = 0.f;
#pragma unroll
    for (int k = 0; k < VK; k++) v += varK[k * CH + c];
    scl[c] = gam[c] * rsqrtf(v * (1.f / (GG * LN)) + EPSV);
}

// ---------- final epilogue: sliced centered bf16 -> out[g][c][l] fp32 ----------
// bid = chunk*8 + sid; chunk picks 16 nodes
__global__ __launch_bounds__(256) void k_epi_t(
    const unsigned short* __restrict__ a, const float* __restrict__ scl,
    const float* __restrict__ bet, float* __restrict__ out)
{
    __shared__ unsigned short lds[16 * 32 * 34];   // [l][g][c pad34]
    const int bid = blockIdx.x;
    const int sid = bid & 7;
    const int chunk = bid >> 3;          // [0,128)
    const int l0 = chunk * 16;
    const int t = threadIdx.x;
    const int sg = sid >> 2;
    const int sc = sid & 3;
    const unsigned short* aBs = a + sid * SLICE;
    {
        const int gl = t & 31;
        const int cq = t >> 5;
#pragma unroll
        for (int i = 0; i < 16; i++) {
            uint2 v = *(const uint2*)&aBs[(size_t)(l0 + i) * 1024 + gl * 32 + cq * 4];
            unsigned short* lp = &lds[(i * 32 + gl) * 34 + cq * 4];
            *(unsigned int*)&lp[0] = v.x;
            *(unsigned int*)&lp[2] = v.y;
        }
    }
    __syncthreads();
#pragma unroll
    for (int it = 0; it < 4; it++) {
        const int p = it * 256 + t;
        const int gl2 = p >> 5;
        const int c2 = p & 31;
        const int cG = sc * 32 + c2;
        const float s = scl[cG], bb = bet[cG];
        float o[16];
#pragma unroll
        for (int l = 0; l < 16; l++)
            o[l] = fmaxf(b2f(lds[(l * 32 + gl2) * 34 + c2]) * s + bb, 0.f);
        float* op = &out[((size_t)(sg * 32 + gl2) * CH + cG) * LN + l0];
#pragma unroll
        for (int l = 0; l < 16; l += 4)
            *(float4*)&op[l] = make_float4(o[l], o[l + 1], o[l + 2], o[l + 3]);
    }
}

extern "C" void kernel_launch(void* const* d_in, const int* in_sizes, int n_in,
                              void* d_out, int out_size, void* d_ws, size_t ws_size,
                              hipStream_t stream) {
    const float* x   = (const float*)d_in[0];
    const int*   ei  = (const int*)d_in[1];
    const float* W1  = (const float*)d_in[2];
    const float* g1  = (const float*)d_in[4];
    const float* be1 = (const float*)d_in[5];
    const float* W2  = (const float*)d_in[6];
    const float* g2  = (const float*)d_in[8];
    const float* be2 = (const float*)d_in[9];
    const float* W3  = (const float*)d_in[10];
    const float* g3  = (const float*)d_in[12];
    const float* be3 = (const float*)d_in[13];
    const int* srcp = ei;
    const int* dstp = ei + EE;

    char* ws = (char*)d_ws;
    size_t pos = 0;
    auto alloc = [&](size_t bytes) -> void* {
        void* p = ws + pos;
        pos = (pos + bytes + 255) & ~(size_t)255;
        return p;
    };
    const size_t big = (size_t)LN * GG * CH * sizeof(unsigned short);  // 33.55 MB
    unsigned short* aB  = (unsigned short*)alloc(big);
    unsigned short* Wt1 = (unsigned short*)alloc(C_0 * CH * 2);
    unsigned short* Wt2 = (unsigned short*)alloc(CH * CH * 2);
    unsigned short* Wt3 = (unsigned short*)alloc(CH * CH * 2);
    int*   cnt   = (int*)alloc(LN * 4);
    int*   offA  = (int*)alloc((LN + 1) * 4);
    int*   cur   = (int*)alloc(LN * 4);
    float* dinv  = (float*)alloc(LN * 4);
    float* selfc = (float*)alloc(LN * 4);
    int*   ssrc  = (int*)alloc(EE * 4);
    float* snorm = (float*)alloc(EE * 4);
    float* varK  = (float*)alloc(VK * CH * 4);
    float* scl   = (float*)alloc(CH * 4);
    unsigned short* hw = (ws_size >= pos + big) ? (unsigned short*)alloc(big)
                                                : (unsigned short*)d_out;

    // graph preprocessing
    hipMemsetAsync(cnt, 0, LN * 4, stream);
    hipMemsetAsync(cur, 0, LN * 4, stream);
    k_deg<<<EE / 256, 256, 0, stream>>>(dstp, cnt);
    k_node<<<LN / 256, 256, 0, stream>>>(cnt, dinv, selfc);
    k_scan<<<1, 256, 0, stream>>>(cnt, offA);
    k_fill<<<EE / 256, 256, 0, stream>>>(srcp, dstp, offA, cur, dinv, ssrc, snorm);
    k_wprep<<<(C_0 * CH) / 256, 256, 0, stream>>>(W1, Wt1, C_0);
    k_wprep<<<(CH * CH) / 256, 256, 0, stream>>>(W2, Wt2, CH);
    k_wprep<<<(CH * CH) / 256, 256, 0, stream>>>(W3, Wt3, CH);

    dim3 mmG(LN / 64, GG);

    // ---- layer 1 ----
    k_mm<C_0, false><<<mmG, 256, 0, stream>>>(x, nullptr, nullptr, nullptr, Wt1, hw);
    hipMemsetAsync(varK, 0, VK * CH * 4, stream);
    k_gnv<<<256 * 8, 256, 0, stream>>>(hw, aB, varK, offA, ssrc, snorm, selfc);
    k_scale<<<1, CH, 0, stream>>>(varK, g1, scl);

    // ---- layer 2 ----
    k_mm<CH, true><<<mmG, 256, 0, stream>>>(nullptr, aB, scl, be1, Wt2, hw);
    hipMemsetAsync(varK, 0, VK * CH * 4, stream);
    k_gnv<<<256 * 8, 256, 0, stream>>>(hw, aB, varK, offA, ssrc, snorm, selfc);
    k_scale<<<1, CH, 0, stream>>>(varK, g2, scl);

    // ---- layer 3 ----
    k_mm<CH, true><<<mmG, 256, 0, stream>>>(nullptr, aB, scl, be2, Wt3, hw);
    hipMemsetAsync(varK, 0, VK * CH * 4, stream);
    k_gnv<<<256 * 8, 256, 0, stream>>>(hw, aB, varK, offA, ssrc, snorm, selfc);
    k_scale<<<1, CH, 0, stream>>>(varK, g3, scl);

    // ---- output ----
    k_epi_t<<<128 * 8, 256, 0, stream>>>(aB, scl, be3, (float*)d_out);
}

// Round 5
// 309.717 us; speedup vs baseline: 1.2465x; 1.2465x over previous
//
#include <hip/hip_runtime.h>
#include <hip/hip_bf16.h>

#define GG 64      // B*N graphs
#define LN 2048    // nodes per graph
#define BB 4       // batch
#define NS 16      // sets per batch
#define EE 16384   // edges
#define C_0 64
#define CH 128
#define EPSV 1e-5f
#define VK 16      // variance atomic spread copies
// sliced layout: 8 slices of (32 graphs x 32 ch); slice id = (g>>5)*4 + (c>>5)
// elem addr = sid*SLICE + l*1024 + (g&31)*32 + (c&31)
#define SLICE ((size_t)LN * 1024)

using bf16x8 = __attribute__((ext_vector_type(8))) short;
using f32x4  = __attribute__((ext_vector_type(4))) float;
using u32x4  = __attribute__((ext_vector_type(4))) unsigned int;

__device__ __forceinline__ float b2f(unsigned short u) {
    union { unsigned int i; float f; } v; v.i = ((unsigned int)u) << 16; return v.f;
}
__device__ __forceinline__ unsigned short f2b(float f) {
    union { float f; unsigned int i; } v; v.f = f;
    unsigned int r = v.i + 0x7fffu + ((v.i >> 16) & 1u);   // RNE
    return (unsigned short)(r >> 16);
}
__device__ __forceinline__ void acc8(float* acc, u32x4 v, float w) {
    acc[0] += w * b2f((unsigned short)(v.x & 0xffffu));
    acc[1] += w * b2f((unsigned short)(v.x >> 16));
    acc[2] += w * b2f((unsigned short)(v.y & 0xffffu));
    acc[3] += w * b2f((unsigned short)(v.y >> 16));
    acc[4] += w * b2f((unsigned short)(v.z & 0xffffu));
    acc[5] += w * b2f((unsigned short)(v.z >> 16));
    acc[6] += w * b2f((unsigned short)(v.w & 0xffffu));
    acc[7] += w * b2f((unsigned short)(v.w >> 16));
}

// ---------- graph preprocessing ----------
__global__ void k_deg(const int* __restrict__ dst, int* __restrict__ cnt) {
    int e = blockIdx.x * blockDim.x + threadIdx.x;
    if (e < EE) atomicAdd(&cnt[dst[e]], 1);
}

__global__ void k_node(const int* __restrict__ cnt, float* __restrict__ dinv,
                       float* __restrict__ selfc) {
    int l = blockIdx.x * blockDim.x + threadIdx.x;
    if (l < LN) {
        float d = (float)cnt[l] + 2.0f;   // improved GCN: A + 2I
        float di = rsqrtf(d);
        dinv[l] = di;
        selfc[l] = 2.0f * di * di;
    }
}

__global__ void k_scan(const int* __restrict__ cnt, int* __restrict__ off) {
    __shared__ int part[256];
    __shared__ int pre[256];
    int t = threadIdx.x;
    int base = t * 8;
    int loc[8];
    int s = 0;
#pragma unroll
    for (int i = 0; i < 8; i++) { loc[i] = cnt[base + i]; s += loc[i]; }
    part[t] = s;
    __syncthreads();
    if (t == 0) {
        int run = 0;
        for (int i = 0; i < 256; i++) { pre[i] = run; run += part[i]; }
        off[LN] = run;
    }
    __syncthreads();
    int run = pre[t];
#pragma unroll
    for (int i = 0; i < 8; i++) { off[base + i] = run; run += loc[i]; }
}

__global__ void k_fill(const int* __restrict__ src, const int* __restrict__ dst,
                       const int* __restrict__ off, int* __restrict__ cur,
                       const float* __restrict__ dinv,
                       int* __restrict__ ssrc, float* __restrict__ snorm) {
    int e = blockIdx.x * blockDim.x + threadIdx.x;
    if (e < EE) {
        int s = src[e], d = dst[e];
        int pos = atomicAdd(&cur[d], 1);
        int idx = off[d] + pos;
        ssrc[idx] = s;
        snorm[idx] = dinv[s] * dinv[d];
    }
}

// ---------- W -> W^T bf16 ----------
__global__ void k_wprep(const float* __restrict__ W, unsigned short* __restrict__ Wt,
                        int K) {
    int idx = blockIdx.x * 256 + threadIdx.x;
    if (idx < K * CH) {
        int k = idx >> 7, c = idx & (CH - 1);
        Wt[c * K + k] = f2b(W[idx]);
    }
}

// ---------- MFMA GEMM: hw[l,g,co] = sum_k A[l,k] * W[k,co] (bf16, fp32 acc) ----------
// FUSE=false: layer 1, A from x fp32 [g][K][LN].
// FUSE=true : A = relu(aPrev * scl + bet)   (aPrev already mean-centered)
template <int K, bool FUSE>
__global__ __launch_bounds__(256) void k_mm(
    const float* __restrict__ X, const unsigned short* __restrict__ Ap,
    const float* __restrict__ scl, const float* __restrict__ bet,
    const unsigned short* __restrict__ Wt, unsigned short* __restrict__ hw)
{
    constexpr int KP = K + 8;                 // LDS k-pad
    __shared__ unsigned short As[64 * KP];
    __shared__ unsigned short Ws[128 * KP];
    const int g = blockIdx.y;
    const int l0 = blockIdx.x * 64;
    const int t = threadIdx.x;
    const int wq = t >> 6;
    const int lane = t & 63;

    // stage W^T tile (c-major, k contiguous)
    {
        const int c = t >> 1;
        const int kq = (t & 1) * (K / 2);
        const unsigned short* wp = Wt + c * K + kq;
        unsigned short* wd = Ws + c * KP + kq;
#pragma unroll
        for (int i = 0; i < K / 2; i += 8)
            *(uint4*)&wd[i] = *(const uint4*)&wp[i];
    }
    if (!FUSE) {
        // x fp32 [g][K][LN] -> As[l][k] bf16 (transpose in LDS)
        const int k = t >> 2;
        const int lq = (t & 3) * 16;
        const float* xp = X + ((size_t)g * K + k) * LN + l0 + lq;
#pragma unroll
        for (int i = 0; i < 16; i += 4) {
            float4 v = *(const float4*)&xp[i];
            As[(lq + i + 0) * KP + k] = f2b(v.x);
            As[(lq + i + 1) * KP + k] = f2b(v.y);
            As[(lq + i + 2) * KP + k] = f2b(v.z);
            As[(lq + i + 3) * KP + k] = f2b(v.w);
        }
    } else {
        // fused prev-layer BN+ReLU during staging; Ap is sliced + centered
        const int l = t >> 2;
        const int sc = t & 3;
        const int kq = sc * 32;
        const int sid = (g >> 5) * 4 + sc;
        const unsigned short* ap = Ap + sid * SLICE + (size_t)(l0 + l) * 1024 +
                                   (g & 31) * 32;
        unsigned short* ad = As + l * KP + kq;
#pragma unroll
        for (int i = 0; i < 32; i += 8) {
            union { uint4 v; unsigned short s[8]; } u;
            u.v = *(const uint4*)&ap[i];
            float4 s0 = *(const float4*)&scl[kq + i];
            float4 s1 = *(const float4*)&scl[kq + i + 4];
            float4 c0 = *(const float4*)&bet[kq + i];
            float4 c1 = *(const float4*)&bet[kq + i + 4];
            union { uint4 v; unsigned short s[8]; } o;
            o.s[0] = f2b(fmaxf(b2f(u.s[0]) * s0.x + c0.x, 0.f));
            o.s[1] = f2b(fmaxf(b2f(u.s[1]) * s0.y + c0.y, 0.f));
            o.s[2] = f2b(fmaxf(b2f(u.s[2]) * s0.z + c0.z, 0.f));
            o.s[3] = f2b(fmaxf(b2f(u.s[3]) * s0.w + c0.w, 0.f));
            o.s[4] = f2b(fmaxf(b2f(u.s[4]) * s1.x + c1.x, 0.f));
            o.s[5] = f2b(fmaxf(b2f(u.s[5]) * s1.y + c1.y, 0.f));
            o.s[6] = f2b(fmaxf(b2f(u.s[6]) * s1.z + c1.z, 0.f));
            o.s[7] = f2b(fmaxf(b2f(u.s[7]) * s1.w + c1.w, 0.f));
            *(uint4*)&ad[i] = o.v;
        }
    }
    __syncthreads();

    f32x4 acc[8];
#pragma unroll
    for (int i = 0; i < 8; i++) acc[i] = (f32x4){0.f, 0.f, 0.f, 0.f};
    const int lr = lane & 15;
    const int kof = (lane >> 4) * 8;
#pragma unroll
    for (int ks = 0; ks < K / 32; ks++) {
        bf16x8 aF = *(const bf16x8*)&As[(wq * 16 + lr) * KP + ks * 32 + kof];
#pragma unroll
        for (int nf = 0; nf < 8; nf++) {
            bf16x8 bF = *(const bf16x8*)&Ws[(nf * 16 + lr) * KP + ks * 32 + kof];
            acc[nf] = __builtin_amdgcn_mfma_f32_16x16x32_bf16(aF, bF, acc[nf], 0, 0, 0);
        }
    }
    __syncthreads();
    // repack D (C/D map: col=lane&15, row=(lane>>4)*4+reg) -> LDS
    unsigned short* Cs = Ws;   // reuse
#pragma unroll
    for (int nf = 0; nf < 8; nf++) {
#pragma unroll
        for (int r = 0; r < 4; r++) {
            int row = wq * 16 + (lane >> 4) * 4 + r;
            int col = nf * 16 + lr;
            Cs[row * 136 + col] = f2b(acc[nf][r]);
        }
    }
    __syncthreads();
    {
        const int l = t >> 2;
        const int sc = t & 3;
        unsigned short* hp = hw + (size_t)((g >> 5) * 4 + sc) * SLICE +
                             (size_t)(l0 + l) * 1024 + (g & 31) * 32;
#pragma unroll
        for (int i = 0; i < 32; i += 8)
            *(uint4*)&hp[i] = *(const uint4*)&Cs[l * 136 + sc * 32 + i];
    }
}

// ---------- fused gather + center + variance, XCD-pinned slices, coalesced ----------
// bid = chunk*8 + sid; 8 nodes per chunk; 256 threads = 2 rows x 128 lanes (16B each)
// thread: tr = t>>7 (row half), ti = t&127; gl = ti>>2 (graph), ch = (ti&3)*8
// n = gl&15 lives in lane bits 2..5 -> shfl_xor butterfly {4,8,16,32}
__global__ __launch_bounds__(256) void k_gnv(
    const unsigned short* __restrict__ hw, unsigned short* __restrict__ a,
    float* __restrict__ varK,
    const int* __restrict__ off, const int* __restrict__ ssrc,
    const float* __restrict__ snorm, const float* __restrict__ selfc)
{
    const int bid = blockIdx.x;
    const int sid = bid & 7;
    const int chunk = bid >> 3;          // [0, 256)
    const int l0 = chunk * 8;
    const int t = threadIdx.x;
    const int tr = t >> 7;
    const int ti = t & 127;
    const int go = ti * 8;               // short offset within 1024-short row
    const unsigned short* hws = hw + sid * SLICE;
    unsigned short* aBs = a + sid * SLICE;

    float vacc[8] = {0.f, 0.f, 0.f, 0.f, 0.f, 0.f, 0.f, 0.f};
#pragma unroll
    for (int i = 0; i < 4; i++) {
        const int l = l0 + i * 2 + tr;
        float acc[8];
        {
            u32x4 v = *(const u32x4*)&hws[(size_t)l * 1024 + go];
            const float sc = selfc[l];
            acc[0] = sc * b2f((unsigned short)(v.x & 0xffffu));
            acc[1] = sc * b2f((unsigned short)(v.x >> 16));
            acc[2] = sc * b2f((unsigned short)(v.y & 0xffffu));
            acc[3] = sc * b2f((unsigned short)(v.y >> 16));
            acc[4] = sc * b2f((unsigned short)(v.z & 0xffffu));
            acc[5] = sc * b2f((unsigned short)(v.z >> 16));
            acc[6] = sc * b2f((unsigned short)(v.w & 0xffffu));
            acc[7] = sc * b2f((unsigned short)(v.w >> 16));
        }
        const int s0 = off[l], s1 = off[l + 1];
        int e = s0;
        for (; e + 4 <= s1; e += 4) {
            int sA = ssrc[e], sB = ssrc[e + 1], sC = ssrc[e + 2], sD = ssrc[e + 3];
            float wA = snorm[e], wB = snorm[e + 1], wC = snorm[e + 2], wD = snorm[e + 3];
            u32x4 vA = *(const u32x4*)&hws[(size_t)sA * 1024 + go];
            u32x4 vB = *(const u32x4*)&hws[(size_t)sB * 1024 + go];
            u32x4 vC = *(const u32x4*)&hws[(size_t)sC * 1024 + go];
            u32x4 vD = *(const u32x4*)&hws[(size_t)sD * 1024 + go];
            acc8(acc, vA, wA); acc8(acc, vB, wB);
            acc8(acc, vC, wC); acc8(acc, vD, wD);
        }
        for (; e < s1; e++) {
            int sA = ssrc[e];
            float wA = snorm[e];
            u32x4 vA = *(const u32x4*)&hws[(size_t)sA * 1024 + go];
            acc8(acc, vA, wA);
        }
        // mean over the 16 sets (lane bits 2..5)
        float m[8];
#pragma unroll
        for (int j = 0; j < 8; j++) m[j] = acc[j];
#pragma unroll
        for (int mask = 4; mask <= 32; mask <<= 1) {
#pragma unroll
            for (int j = 0; j < 8; j++) m[j] += __shfl_xor(m[j], mask);
        }
        u32x4 o;
        unsigned short ob[8];
#pragma unroll
        for (int j = 0; j < 8; j++) {
            float d = acc[j] - m[j] * (1.f / NS);   // centered value
            vacc[j] += d * d;
            ob[j] = f2b(d);
        }
        o.x = (unsigned int)ob[0] | ((unsigned int)ob[1] << 16);
        o.y = (unsigned int)ob[2] | ((unsigned int)ob[3] << 16);
        o.z = (unsigned int)ob[4] | ((unsigned int)ob[5] << 16);
        o.w = (unsigned int)ob[6] | ((unsigned int)ob[7] << 16);
        __builtin_nontemporal_store(o, (u32x4*)&aBs[(size_t)l * 1024 + go]);
    }
    // deferred variance butterfly + one atomic burst from lanes 0..3 of each wave
#pragma unroll
    for (int mask = 4; mask <= 32; mask <<= 1) {
#pragma unroll
        for (int j = 0; j < 8; j++) vacc[j] += __shfl_xor(vacc[j], mask);
    }
    if ((t & 63) < 4) {
        float* vp = &varK[(chunk & (VK - 1)) * CH + (sid & 3) * 32 + (t & 3) * 8];
#pragma unroll
        for (int j = 0; j < 8; j++) atomicAdd(&vp[j], vacc[j]);
    }
}

__global__ void k_scale(const float* __restrict__ varK, const float* __restrict__ gam,
                        float* __restrict__ scl) {
    int c = threadIdx.x;
    float v = 0.f;
#pragma unroll
    for (int k = 0; k < VK; k++) v += varK[k * CH + c];
    scl[c] = gam[c] * rsqrtf(v * (1.f / (GG * LN)) + EPSV);
}

// ---------- final epilogue: sliced centered bf16 -> out[g][c][l] fp32 ----------
// bid = chunk*8 + sid; chunk picks 16 nodes
__global__ __launch_bounds__(256) void k_epi_t(
    const unsigned short* __restrict__ a, const float* __restrict__ scl,
    const float* __restrict__ bet, float* __restrict__ out)
{
    __shared__ unsigned short lds[16 * 32 * 40];   // [l][g][c pad40] (16B-aligned rows)
    const int bid = blockIdx.x;
    const int sid = bid & 7;
    const int chunk = bid >> 3;          // [0,128)
    const int l0 = chunk * 16;
    const int t = threadIdx.x;
    const int sg = sid >> 2;
    const int sc = sid & 3;
    const unsigned short* aBs = a + sid * SLICE;
    {
        const int tr = t >> 7;
        const int ti = t & 127;
        const int gl = ti >> 2;
        const int c0 = (ti & 3) * 8;
#pragma unroll
        for (int i = 0; i < 8; i++) {
            const int lloc = i * 2 + tr;
            uint4 v = *(const uint4*)&aBs[(size_t)(l0 + lloc) * 1024 + ti * 8];
            *(uint4*)&lds[(lloc * 32 + gl) * 40 + c0] = v;
        }
    }
    __syncthreads();
#pragma unroll
    for (int it = 0; it < 4; it++) {
        const int p = it * 256 + t;
        const int gl2 = p >> 5;
        const int c2 = p & 31;
        const int cG = sc * 32 + c2;
        const float s = scl[cG], bb = bet[cG];
        float o[16];
#pragma unroll
        for (int l = 0; l < 16; l++)
            o[l] = fmaxf(b2f(lds[(l * 32 + gl2) * 40 + c2]) * s + bb, 0.f);
        float* op = &out[((size_t)(sg * 32 + gl2) * CH + cG) * LN + l0];
#pragma unroll
        for (int l = 0; l < 16; l += 4)
            *(float4*)&op[l] = make_float4(o[l], o[l + 1], o[l + 2], o[l + 3]);
    }
}

extern "C" void kernel_launch(void* const* d_in, const int* in_sizes, int n_in,
                              void* d_out, int out_size, void* d_ws, size_t ws_size,
                              hipStream_t stream) {
    const float* x   = (const float*)d_in[0];
    const int*   ei  = (const int*)d_in[1];
    const float* W1  = (const float*)d_in[2];
    const float* g1  = (const float*)d_in[4];
    const float* be1 = (const float*)d_in[5];
    const float* W2  = (const float*)d_in[6];
    const float* g2  = (const float*)d_in[8];
    const float* be2 = (const float*)d_in[9];
    const float* W3  = (const float*)d_in[10];
    const float* g3  = (const float*)d_in[12];
    const float* be3 = (const float*)d_in[13];
    const int* srcp = ei;
    const int* dstp = ei + EE;

    char* ws = (char*)d_ws;
    size_t pos = 0;
    auto alloc = [&](size_t bytes) -> void* {
        void* p = ws + pos;
        pos = (pos + bytes + 255) & ~(size_t)255;
        return p;
    };
    const size_t big = (size_t)LN * GG * CH * sizeof(unsigned short);  // 33.55 MB
    unsigned short* aB  = (unsigned short*)alloc(big);
    unsigned short* Wt1 = (unsigned short*)alloc(C_0 * CH * 2);
    unsigned short* Wt2 = (unsigned short*)alloc(CH * CH * 2);
    unsigned short* Wt3 = (unsigned short*)alloc(CH * CH * 2);
    int*   cnt   = (int*)alloc(LN * 4);
    int*   offA  = (int*)alloc((LN + 1) * 4);
    int*   cur   = (int*)alloc(LN * 4);
    float* dinv  = (float*)alloc(LN * 4);
    float* selfc = (float*)alloc(LN * 4);
    int*   ssrc  = (int*)alloc(EE * 4);
    float* snorm = (float*)alloc(EE * 4);
    float* varK  = (float*)alloc(VK * CH * 4);
    float* scl   = (float*)alloc(CH * 4);
    unsigned short* hw = (ws_size >= pos + big) ? (unsigned short*)alloc(big)
                                                : (unsigned short*)d_out;

    // graph preprocessing
    hipMemsetAsync(cnt, 0, LN * 4, stream);
    hipMemsetAsync(cur, 0, LN * 4, stream);
    k_deg<<<EE / 256, 256, 0, stream>>>(dstp, cnt);
    k_node<<<LN / 256, 256, 0, stream>>>(cnt, dinv, selfc);
    k_scan<<<1, 256, 0, stream>>>(cnt, offA);
    k_fill<<<EE / 256, 256, 0, stream>>>(srcp, dstp, offA, cur, dinv, ssrc, snorm);
    k_wprep<<<(C_0 * CH) / 256, 256, 0, stream>>>(W1, Wt1, C_0);
    k_wprep<<<(CH * CH) / 256, 256, 0, stream>>>(W2, Wt2, CH);
    k_wprep<<<(CH * CH) / 256, 256, 0, stream>>>(W3, Wt3, CH);

    dim3 mmG(LN / 64, GG);

    // ---- layer 1 ----
    k_mm<C_0, false><<<mmG, 256, 0, stream>>>(x, nullptr, nullptr, nullptr, Wt1, hw);
    hipMemsetAsync(varK, 0, VK * CH * 4, stream);
    k_gnv<<<256 * 8, 256, 0, stream>>>(hw, aB, varK, offA, ssrc, snorm, selfc);
    k_scale<<<1, CH, 0, stream>>>(varK, g1, scl);

    // ---- layer 2 ----
    k_mm<CH, true><<<mmG, 256, 0, stream>>>(nullptr, aB, scl, be1, Wt2, hw);
    hipMemsetAsync(varK, 0, VK * CH * 4, stream);
    k_gnv<<<256 * 8, 256, 0, stream>>>(hw, aB, varK, offA, ssrc, snorm, selfc);
    k_scale<<<1, CH, 0, stream>>>(varK, g2, scl);

    // ---- layer 3 ----
    k_mm<CH, true><<<mmG, 256, 0, stream>>>(nullptr, aB, scl, be2, Wt3, hw);
    hipMemsetAsync(varK, 0, VK * CH * 4, stream);
    k_gnv<<<256 * 8, 256, 0, stream>>>(hw, aB, varK, offA, ssrc, snorm, selfc);
    k_scale<<<1, CH, 0, stream>>>(varK, g3, scl);

    // ---- output ----
    k_epi_t<<<128 * 8, 256, 0, stream>>>(aB, scl, be3, (float*)d_out);
}